// Round 1
// baseline (121.532 us; speedup 1.0000x reference)
//
#include <hip/hip_runtime.h>
#include <hip/hip_cooperative_groups.h>

namespace cg = cooperative_groups;

// BatchInfoNCELoss: B=9, H=W=768, C=3, PATCH=3 (D=27), RADIUS=2 -> M=13 offsets,
// N_SAMPLES=100, TEMPERATURE=0.5, K=B-1=8.
//
// final = sum_n [ sum_{b, j!=b, m valid} dot(a[b,n], v[j,n,m])^2 ]
//               * (1/T^2) / (K * counts_n * B * N)
// where a[b,n] == v[b,n,m=6] (offset (0,0)), vectors are edge-clamped 3x3x3
// patches normalized to unit L2.
//
// Single cooperative launch: per-block anchor partials -> grid.sync() ->
// block 0 reduces the 100 partials. (Timed region is dominated by the
// harness' 2x256MiB workspace poison fills ~83us; only launch count is
// controllable, hence the fusion.)

constexpr int BB = 9;
constexpr int HH = 768;
constexpr int WW = 768;
constexpr int CC = 3;
constexpr int D  = 27;   // PATCH*PATCH*C
constexpr int M  = 13;   // offsets with dy^2+dx^2 <= 4
constexpr int NS = 100;  // anchors
constexpr int M0 = 6;    // index of offset (0,0) in dy-major order

__global__ __launch_bounds__(128)
void BatchInfoNCELoss_fused_kernel(const float* __restrict__ latents,
                                   const int* __restrict__ aidx,
                                   float* __restrict__ partial,
                                   float* __restrict__ out) {
    const int n = blockIdx.x;   // anchor id
    const int t = threadIdx.x;  // 0..127

    __shared__ float v[BB * M][D + 1];  // 117 normalized patch vectors (+1 pad)
    __shared__ float wsum[2];

    const int ODY[M] = {-2, -1, -1, -1, 0, 0, 0, 0, 0, 1, 1, 1, 2};
    const int ODX[M] = { 0, -1,  0,  1,-2,-1, 0, 1, 2,-1, 0, 1, 0};

    const int apos = aidx[n];
    const int ay = apos / WW;
    const int ax = apos - ay * WW;

    // Stage 1: compute 117 normalized patch vectors into LDS.
    for (int task = t; task < BB * M; task += 128) {
        const int b = task / M;
        const int m = task - b * M;
        const int ny = ay + ODY[m];
        const int nx = ax + ODX[m];
        // clipped position (reference clips pos; invalid ones masked later)
        const int cy = min(max(ny, 0), HH - 1);
        const int cx = min(max(nx, 0), WW - 1);

        float vec[D];
        float nrm2 = 0.0f;
        int k = 0;
        #pragma unroll
        for (int dy = -1; dy <= 1; ++dy) {
            const int py = min(max(cy + dy, 0), HH - 1);
            #pragma unroll
            for (int dx = -1; dx <= 1; ++dx) {
                const int px = min(max(cx + dx, 0), WW - 1);
                const float* p = latents + (((size_t)b * HH + py) * WW + px) * CC;
                #pragma unroll
                for (int c = 0; c < CC; ++c) {
                    const float f = p[c];
                    vec[k++] = f;
                    nrm2 += f * f;
                }
            }
        }
        const float inv = 1.0f / fmaxf(sqrtf(nrm2), 1e-12f);
        #pragma unroll
        for (int kk = 0; kk < D; ++kk) v[task][kk] = vec[kk] * inv;
    }

    // Validity mask + count (cheap; computed redundantly by every thread).
    int validmask = 0;
    int counts = 0;
    #pragma unroll
    for (int m = 0; m < M; ++m) {
        const int ny = ay + ODY[m];
        const int nx = ax + ODX[m];
        const int ok = (ny >= 0) && (ny < HH) && (nx >= 0) && (nx < WW);
        validmask |= ok << m;
        counts += ok;
    }

    __syncthreads();

    // Stage 2: 9*9*13 = 1053 (b,j,m) dot-square tasks; skip b==j and invalid m.
    float acc = 0.0f;
    for (int task = t; task < BB * BB * M; task += 128) {
        const int b = task / (BB * M);
        const int rem = task - b * (BB * M);
        const int j = rem / M;
        const int m = rem - j * M;
        if (b == j) continue;
        if (!((validmask >> m) & 1)) continue;
        const float* a = v[b * M + M0];
        const float* u = v[j * M + m];
        float dot = 0.0f;
        #pragma unroll
        for (int kk = 0; kk < D; ++kk) dot += a[kk] * u[kk];
        acc += dot * dot;
    }

    // Block reduction (2 waves of 64).
    #pragma unroll
    for (int off = 32; off > 0; off >>= 1) acc += __shfl_down(acc, off, 64);
    if ((t & 63) == 0) wsum[t >> 6] = acc;
    __syncthreads();
    if (t == 0) {
        const float s = wsum[0] + wsum[1];
        // (1/T^2)=4 ; K=8 ; mean over B*N = 900
        const float scale = 4.0f / (8.0f * (float)counts * (float)(BB * NS));
        partial[n] = s * scale;
        __threadfence();  // make partial[n] visible device-wide before grid sync
    }

    // Grid-wide sync, then block 0 performs the final 100-element reduction.
    cg::this_grid().sync();

    if (n == 0) {
        float a = (t < NS) ? partial[t] : 0.0f;
        #pragma unroll
        for (int off = 32; off > 0; off >>= 1) a += __shfl_down(a, off, 64);
        if ((t & 63) == 0) wsum[t >> 6] = a;
        __syncthreads();
        if (t == 0) out[0] = wsum[0] + wsum[1];
    }
}

extern "C" void kernel_launch(void* const* d_in, const int* in_sizes, int n_in,
                              void* d_out, int out_size, void* d_ws, size_t ws_size,
                              hipStream_t stream) {
    const float* latents = (const float*)d_in[0];
    const int*   aidx    = (const int*)d_in[1];
    float* out     = (float*)d_out;
    float* partial = (float*)d_ws;  // NS floats of scratch

    void* args[] = { (void*)&latents, (void*)&aidx, (void*)&partial, (void*)&out };
    hipLaunchCooperativeKernel((const void*)BatchInfoNCELoss_fused_kernel,
                               dim3(NS), dim3(128), args, 0, stream);
}

// Round 2
// 90.300 us; speedup vs baseline: 1.3459x; 1.3459x over previous
//
#include <hip/hip_runtime.h>

// BatchInfoNCELoss: B=9, H=W=768, C=3, PATCH=3 (D=27), RADIUS=2 -> M=13 offsets,
// N_SAMPLES=100, TEMPERATURE=0.5, K=B-1=8.
//
// final = sum_n [ sum_{b, j!=b, m valid} dot(a[b,n], v[j,n,m])^2 ]
//               * (1/T^2) / (K * counts_n * B * N)
// where a[b,n] == v[b,n,m=6] (offset (0,0)), vectors are edge-clamped 3x3x3
// patches normalized to unit L2.
//
// Single regular launch (cooperative launch regressed +32us under graph
// capture -- R1 post-mortem). Last-finishing block does the final reduce,
// coordinated via module-scope __device__ globals (persist across launches,
// zero-initialized at load, never poisoned by the harness). All cross-block
// data moves through device-scope atomics -> coherent across XCDs, no
// dispatch-order assumptions.

constexpr int BB = 9;
constexpr int HH = 768;
constexpr int WW = 768;
constexpr int CC = 3;
constexpr int D  = 27;   // PATCH*PATCH*C
constexpr int M  = 13;   // offsets with dy^2+dx^2 <= 4
constexpr int NS = 100;  // anchors
constexpr int M0 = 6;    // index of offset (0,0) in dy-major order

__device__ float g_partial[128];  // anchor partials (atomically written/read)
__device__ int   g_counter = 0;   // blocks-done counter; reset to 0 each launch

__global__ __launch_bounds__(128)
void BatchInfoNCELoss_fused_kernel(const float* __restrict__ latents,
                                   const int* __restrict__ aidx,
                                   float* __restrict__ out) {
    const int n = blockIdx.x;   // anchor id
    const int t = threadIdx.x;  // 0..127

    __shared__ float v[BB * M][D + 1];  // 117 normalized patch vectors (+1 pad)
    __shared__ float wsum[2];
    __shared__ int   isLast;

    const int ODY[M] = {-2, -1, -1, -1, 0, 0, 0, 0, 0, 1, 1, 1, 2};
    const int ODX[M] = { 0, -1,  0,  1,-2,-1, 0, 1, 2,-1, 0, 1, 0};

    const int apos = aidx[n];
    const int ay = apos / WW;
    const int ax = apos - ay * WW;

    // Stage 1: compute 117 normalized patch vectors into LDS.
    for (int task = t; task < BB * M; task += 128) {
        const int b = task / M;
        const int m = task - b * M;
        const int ny = ay + ODY[m];
        const int nx = ax + ODX[m];
        // clipped position (reference clips pos; invalid ones masked later)
        const int cy = min(max(ny, 0), HH - 1);
        const int cx = min(max(nx, 0), WW - 1);

        float vec[D];
        float nrm2 = 0.0f;
        int k = 0;
        #pragma unroll
        for (int dy = -1; dy <= 1; ++dy) {
            const int py = min(max(cy + dy, 0), HH - 1);
            #pragma unroll
            for (int dx = -1; dx <= 1; ++dx) {
                const int px = min(max(cx + dx, 0), WW - 1);
                const float* p = latents + (((size_t)b * HH + py) * WW + px) * CC;
                #pragma unroll
                for (int c = 0; c < CC; ++c) {
                    const float f = p[c];
                    vec[k++] = f;
                    nrm2 += f * f;
                }
            }
        }
        const float inv = 1.0f / fmaxf(sqrtf(nrm2), 1e-12f);
        #pragma unroll
        for (int kk = 0; kk < D; ++kk) v[task][kk] = vec[kk] * inv;
    }

    // Validity mask + count (cheap; computed redundantly by every thread).
    int validmask = 0;
    int counts = 0;
    #pragma unroll
    for (int m = 0; m < M; ++m) {
        const int ny = ay + ODY[m];
        const int nx = ax + ODX[m];
        const int ok = (ny >= 0) && (ny < HH) && (nx >= 0) && (nx < WW);
        validmask |= ok << m;
        counts += ok;
    }

    __syncthreads();

    // Stage 2: 9*9*13 = 1053 (b,j,m) dot-square tasks; skip b==j and invalid m.
    float acc = 0.0f;
    for (int task = t; task < BB * BB * M; task += 128) {
        const int b = task / (BB * M);
        const int rem = task - b * (BB * M);
        const int j = rem / M;
        const int m = rem - j * M;
        if (b == j) continue;
        if (!((validmask >> m) & 1)) continue;
        const float* a = v[b * M + M0];
        const float* u = v[j * M + m];
        float dot = 0.0f;
        #pragma unroll
        for (int kk = 0; kk < D; ++kk) dot += a[kk] * u[kk];
        acc += dot * dot;
    }

    // Block reduction (2 waves of 64).
    #pragma unroll
    for (int off = 32; off > 0; off >>= 1) acc += __shfl_down(acc, off, 64);
    if ((t & 63) == 0) wsum[t >> 6] = acc;
    __syncthreads();

    if (t == 0) {
        const float s = wsum[0] + wsum[1];
        // (1/T^2)=4 ; K=8 ; mean over B*N = 900
        const float scale = 4.0f / (8.0f * (float)counts * (float)(BB * NS));
        // Device-scope atomic store: coherent across XCDs, no fence subtlety
        // for the data word itself.
        atomicExch(&g_partial[n], s * scale);
        __threadfence();  // order the partial publish before the counter bump
        const int old = atomicAdd(&g_counter, 1);
        isLast = (old == NS - 1);
    }
    __syncthreads();

    // The block that observed counter==NS knows all partials are published.
    if (isLast) {
        __threadfence();  // acquire side
        // Atomic read: goes to the coherence point, immune to stale per-XCD L2.
        float a = (t < NS) ? atomicAdd(&g_partial[t], 0.0f) : 0.0f;
        #pragma unroll
        for (int off = 32; off > 0; off >>= 1) a += __shfl_down(a, off, 64);
        if ((t & 63) == 0) wsum[t >> 6] = a;
        __syncthreads();
        if (t == 0) {
            out[0] = wsum[0] + wsum[1];
            atomicExch(&g_counter, 0);  // reset for next graph replay
        }
    }
}

extern "C" void kernel_launch(void* const* d_in, const int* in_sizes, int n_in,
                              void* d_out, int out_size, void* d_ws, size_t ws_size,
                              hipStream_t stream) {
    const float* latents = (const float*)d_in[0];
    const int*   aidx    = (const int*)d_in[1];
    float* out = (float*)d_out;
    (void)d_ws; (void)ws_size;

    BatchInfoNCELoss_fused_kernel<<<NS, 128, 0, stream>>>(latents, aidx, out);
}